// Round 1
// baseline (1012.482 us; speedup 1.0000x reference)
//
#include <hip/hip_runtime.h>

// SimpleRNN: B=16384, T=2048, I=1, H=20, O=1, fp32.
// Decomposition: 4 threads per batch element, each owns 5 hidden rows.
// h-state distributed across the quad; exchanged per step via in-wave __shfl.
// 65536 threads = 1024 waves = 1 wave per SIMD across the whole chip.

#define RNN_T 2048
#define RNN_H 20
#define RNN_B 16384

__device__ __forceinline__ float tanh_fast(float a) {
    // tanh(a) = 1 - 2/(exp2(2*log2e*a)+1); exact limits at +/-inf.
    float e = __builtin_amdgcn_exp2f(a * 2.885390081777927f);
    float r = __builtin_amdgcn_rcpf(e + 1.0f);
    return fmaf(-2.0f, r, 1.0f);
}

__launch_bounds__(256, 1)
__global__ void rnn_fwd(const float* __restrict__ x,
                        const float* __restrict__ W_ih,
                        const float* __restrict__ W_hh,
                        const float* __restrict__ b_ih,
                        const float* __restrict__ b_hh,
                        const float* __restrict__ W_fc,
                        const float* __restrict__ b_fc,
                        float* __restrict__ out) {
    const int gid  = blockIdx.x * blockDim.x + threadIdx.x;
    const int b    = gid >> 2;        // batch element
    const int part = gid & 3;         // which 5 rows this thread owns
    const int lane = threadIdx.x & 63;
    const int qbase = lane & ~3;      // first lane of this quad

    // Per-thread weights: rows o = part*5 + i  (o indexes H)
    float W[5][RNN_H];                // W_hh rows
    float wih[5], bias[5], wfc[5];
#pragma unroll
    for (int i = 0; i < 5; ++i) {
        const int o = part * 5 + i;
        wih[i]  = W_ih[o];            // W_ih is [H][1]
        bias[i] = b_ih[o] + b_hh[o];
        wfc[i]  = W_fc[o];            // W_fc is [1][H]
#pragma unroll
        for (int j = 0; j < RNN_H; ++j) W[i][j] = W_hh[o * RNN_H + j];
    }

    float h[5];
#pragma unroll
    for (int i = 0; i < 5; ++i) h[i] = 0.0f;

    const float4* x4 = (const float4*)(x + (size_t)b * RNN_T);

    for (int t4 = 0; t4 < RNN_T / 4; ++t4) {
        const float4 xv = x4[t4];     // same addr for all 4 lanes of the quad (L1 broadcast)
        float xs[4] = {xv.x, xv.y, xv.z, xv.w};
#pragma unroll
        for (int s = 0; s < 4; ++s) {
            // Gather full h[20] from the quad. All lanes run in lockstep, so
            // every shuffle reads the PREVIOUS step's h before anyone updates.
            float hall[RNN_H];
#pragma unroll
            for (int q = 0; q < 4; ++q) {
#pragma unroll
                for (int i = 0; i < 5; ++i) {
                    hall[q * 5 + i] = __shfl(h[i], qbase + q, 64);
                }
            }
#pragma unroll
            for (int o = 0; o < 5; ++o) {
                float acc = fmaf(xs[s], wih[o], bias[o]);
#pragma unroll
                for (int j = 0; j < RNN_H; ++j)
                    acc = fmaf(W[o][j], hall[j], acc);
                h[o] = tanh_fast(acc);
            }
        }
    }

    // Output: sigmoid(sum_h hT[h]*W_fc[h] + b_fc), one scalar per batch.
    float p = 0.0f;
#pragma unroll
    for (int i = 0; i < 5; ++i) p = fmaf(h[i], wfc[i], p);
    p += __shfl_xor(p, 1, 64);
    p += __shfl_xor(p, 2, 64);
    if (part == 0) {
        const float z = p + b_fc[0];
        const float e = __builtin_amdgcn_exp2f(-1.4426950408889634f * z);
        out[b] = __builtin_amdgcn_rcpf(1.0f + e);
    }
}

extern "C" void kernel_launch(void* const* d_in, const int* in_sizes, int n_in,
                              void* d_out, int out_size, void* d_ws, size_t ws_size,
                              hipStream_t stream) {
    const float* x    = (const float*)d_in[0];
    const float* W_ih = (const float*)d_in[1];
    const float* W_hh = (const float*)d_in[2];
    const float* b_ih = (const float*)d_in[3];
    const float* b_hh = (const float*)d_in[4];
    const float* W_fc = (const float*)d_in[5];
    const float* b_fc = (const float*)d_in[6];
    float* out = (float*)d_out;

    const int threads = RNN_B * 4;    // 65536
    const int block   = 256;
    rnn_fwd<<<threads / block, block, 0, stream>>>(x, W_ih, W_hh, b_ih, b_hh,
                                                   W_fc, b_fc, out);
}

// Round 2
// 760.437 us; speedup vs baseline: 1.3314x; 1.3314x over previous
//
#include <hip/hip_runtime.h>

// SimpleRNN: B=16384, T=2048, I=1, H=20, O=1, fp32.
// 4 threads per batch element, each owns 5 hidden rows (h distributed across
// a quad). Round-2 changes vs round-1 (950 us, VGPR=84 -> weights in scratch):
//  - all per-thread state is macro-generated NAMED SCALARS so the 100 W_hh
//    weights live in VGPRs (1 wave/SIMD -> 512-VGPR budget, pressure is free)
//  - quad broadcast of h via DPP quad_perm (VALU pipe) instead of
//    __shfl/ds_bpermute (LDS pipe, ~30cyc at the head of every step's chain)

#define RNN_T 2048
#define RNN_H 20
#define RNN_B 16384

template <int CTRL>
__device__ __forceinline__ float qb(float v) {
    // v_mov_b32_dpp quad_perm broadcast: CTRL = q * 0x55 broadcasts quad-lane q.
    return __builtin_bit_cast(
        float, __builtin_amdgcn_mov_dpp(__builtin_bit_cast(int, v), CTRL, 0xF, 0xF, true));
}

__device__ __forceinline__ float tanh_fast(float a) {
    // tanh(a) = 1 - 2/(exp2(2*log2e*a)+1); exact limits at +/-inf.
    float e = __builtin_amdgcn_exp2f(a * 2.885390081777927f);
    float r = __builtin_amdgcn_rcpf(e + 1.0f);
    return fmaf(-2.0f, r, 1.0f);
}

// Apply M(R,C) for C = 0..19
#define COLS(M, R)                                                              \
    M(R, 0) M(R, 1) M(R, 2) M(R, 3) M(R, 4) M(R, 5) M(R, 6) M(R, 7) M(R, 8)    \
    M(R, 9) M(R, 10) M(R, 11) M(R, 12) M(R, 13) M(R, 14) M(R, 15) M(R, 16)     \
    M(R, 17) M(R, 18) M(R, 19)

#define DECLW(R, C) float w##R##_##C = Wp[(R) * RNN_H + (C)];
#define ACC(R, C) acc##R = fmaf(w##R##_##C, ha##C, acc##R);

// One RNN step. Reads h0..h4 (previous step, all quad lanes in lockstep),
// writes h0..h4. ha{q*5+i} = quad-lane q's h{i}.
#define STEP(XS)                                                                 \
    do {                                                                         \
        float ha0 = qb<0x00>(h0), ha1 = qb<0x00>(h1), ha2 = qb<0x00>(h2),        \
              ha3 = qb<0x00>(h3), ha4 = qb<0x00>(h4);                            \
        float ha5 = qb<0x55>(h0), ha6 = qb<0x55>(h1), ha7 = qb<0x55>(h2),        \
              ha8 = qb<0x55>(h3), ha9 = qb<0x55>(h4);                            \
        float ha10 = qb<0xAA>(h0), ha11 = qb<0xAA>(h1), ha12 = qb<0xAA>(h2),     \
              ha13 = qb<0xAA>(h3), ha14 = qb<0xAA>(h4);                          \
        float ha15 = qb<0xFF>(h0), ha16 = qb<0xFF>(h1), ha17 = qb<0xFF>(h2),     \
              ha18 = qb<0xFF>(h3), ha19 = qb<0xFF>(h4);                          \
        float acc0 = fmaf(XS, wih0, bias0);                                      \
        float acc1 = fmaf(XS, wih1, bias1);                                      \
        float acc2 = fmaf(XS, wih2, bias2);                                      \
        float acc3 = fmaf(XS, wih3, bias3);                                      \
        float acc4 = fmaf(XS, wih4, bias4);                                      \
        COLS(ACC, 0) COLS(ACC, 1) COLS(ACC, 2) COLS(ACC, 3) COLS(ACC, 4)         \
        h0 = tanh_fast(acc0);                                                    \
        h1 = tanh_fast(acc1);                                                    \
        h2 = tanh_fast(acc2);                                                    \
        h3 = tanh_fast(acc3);                                                    \
        h4 = tanh_fast(acc4);                                                    \
    } while (0)

__launch_bounds__(256, 1)
__global__ void rnn_fwd(const float* __restrict__ x,
                        const float* __restrict__ W_ih,
                        const float* __restrict__ W_hh,
                        const float* __restrict__ b_ih,
                        const float* __restrict__ b_hh,
                        const float* __restrict__ W_fc,
                        const float* __restrict__ b_fc,
                        float* __restrict__ out) {
    const int gid  = blockIdx.x * blockDim.x + threadIdx.x;
    const int b    = gid >> 2;   // batch element
    const int part = gid & 3;    // quad-lane == which 5 rows this thread owns

    const float* Wp = W_hh + part * 5 * RNN_H;
    COLS(DECLW, 0) COLS(DECLW, 1) COLS(DECLW, 2) COLS(DECLW, 3) COLS(DECLW, 4)

    const int o0 = part * 5;
    float wih0 = W_ih[o0 + 0], wih1 = W_ih[o0 + 1], wih2 = W_ih[o0 + 2],
          wih3 = W_ih[o0 + 3], wih4 = W_ih[o0 + 4];
    float bias0 = b_ih[o0 + 0] + b_hh[o0 + 0], bias1 = b_ih[o0 + 1] + b_hh[o0 + 1],
          bias2 = b_ih[o0 + 2] + b_hh[o0 + 2], bias3 = b_ih[o0 + 3] + b_hh[o0 + 3],
          bias4 = b_ih[o0 + 4] + b_hh[o0 + 4];
    float wfc0 = W_fc[o0 + 0], wfc1 = W_fc[o0 + 1], wfc2 = W_fc[o0 + 2],
          wfc3 = W_fc[o0 + 3], wfc4 = W_fc[o0 + 4];

    float h0 = 0.0f, h1 = 0.0f, h2 = 0.0f, h3 = 0.0f, h4 = 0.0f;

    const float4* x4 = (const float4*)(x + (size_t)b * RNN_T);

#pragma unroll 1
    for (int t4 = 0; t4 < RNN_T / 4; ++t4) {
        const float4 xv = x4[t4];  // same addr across the quad (cache broadcast)
        STEP(xv.x);
        STEP(xv.y);
        STEP(xv.z);
        STEP(xv.w);
    }

    // out[b] = sigmoid(sum_o h[o]*wfc[o] + b_fc)
    float p = fmaf(h0, wfc0, 0.0f);
    p = fmaf(h1, wfc1, p);
    p = fmaf(h2, wfc2, p);
    p = fmaf(h3, wfc3, p);
    p = fmaf(h4, wfc4, p);
    p += __shfl_xor(p, 1, 64);
    p += __shfl_xor(p, 2, 64);
    if (part == 0) {
        const float z = p + b_fc[0];
        const float e = __builtin_amdgcn_exp2f(-1.4426950408889634f * z);
        out[b] = __builtin_amdgcn_rcpf(1.0f + e);
    }
}

extern "C" void kernel_launch(void* const* d_in, const int* in_sizes, int n_in,
                              void* d_out, int out_size, void* d_ws, size_t ws_size,
                              hipStream_t stream) {
    const float* x    = (const float*)d_in[0];
    const float* W_ih = (const float*)d_in[1];
    const float* W_hh = (const float*)d_in[2];
    const float* b_ih = (const float*)d_in[3];
    const float* b_hh = (const float*)d_in[4];
    const float* W_fc = (const float*)d_in[5];
    const float* b_fc = (const float*)d_in[6];
    float* out = (float*)d_out;

    const int threads = RNN_B * 4;  // 65536 = 1024 waves = 1 wave/SIMD chip-wide
    const int block   = 256;
    rnn_fwd<<<threads / block, block, 0, stream>>>(x, W_ih, W_hh, b_ih, b_hh,
                                                   W_fc, b_fc, out);
}